// Round 5
// baseline (2101.702 us; speedup 1.0000x reference)
//
#include <hip/hip_runtime.h>
#include <stdint.h>

#define B_ 8
#define D_ 128
#define T_ 4096
#define Q_ 30
#define C_ 1024

typedef __attribute__((ext_vector_type(8))) _Float16 half8;
typedef __attribute__((ext_vector_type(4))) float float4_;

// row-major fp16 codebook image [Q*C][128] — B-fragments load straight from here.
__device__ __align__(16) _Float16 g_half[(size_t)Q_*C_*D_];

// ---------------- prep 1: per-code ||c||^2, fp64 accumulation ----------------
__global__ void rvq_prep(const float* __restrict__ cb, float* __restrict__ sumsq){
  int g    = blockIdx.x*128 + (threadIdx.x>>1);
  int half = threadIdx.x & 1;
  const float* src = cb + (size_t)g*D_ + half*64;
  double s = 0.0;
#pragma unroll
  for (int i=0;i<64;i+=4){
    float4_ f = *(const float4_*)(src+i);
    s += (double)f.x*f.x + (double)f.y*f.y + (double)f.z*f.z + (double)f.w*f.w;
  }
  s += __shfl_xor(s, 1);
  if (!half) sumsq[g] = (float)s;
}

// ---------------- prep 2: fp32 -> fp16 codebook, row-major -------------------
__global__ void rvq_h(const float* __restrict__ cb){
  const size_t i = ((size_t)blockIdx.x*256 + threadIdx.x)*8;
  float4_ f0 = *(const float4_*)(cb + i);
  float4_ f1 = *(const float4_*)(cb + i + 4);
  half8 h;
  h[0]=(_Float16)f0.x; h[1]=(_Float16)f0.y; h[2]=(_Float16)f0.z; h[3]=(_Float16)f0.w;
  h[4]=(_Float16)f1.x; h[5]=(_Float16)f1.y; h[6]=(_Float16)f1.z; h[7]=(_Float16)f1.w;
  *(half8*)(g_half + i) = h;
}

// --- main: 30-step RVQ. 16 rows/wave, 512 blocks, 2 blocks/CU.
// Round 0-4 synthesis:
//  - fp64 residual chain is semantically required (R3: fp32 -> absmax 6.86).
//  - 2 waves/SIMD requires total regs <= 256 (R2: unconstrained alloc burns
//    >256 and locks 1 wave/SIMD).
//  - fp64 rmast in registers under the (256,2) cap gets parked in AGPRs and
//    every rescore/update access pays accvgpr moves; plus rolled single-buffer
//    loop exposes L2 latency (R4: 2156us despite 24% occupancy).
//  => rmast lives in LDS (wave-private, stride 129 doubles -> 2-way bank
//     aliasing = free). fp32 shadow in regs feeds the fp16 A-fragments.
//     Register demand drops to ~160 -> dbuf prefetch + full-unroll g-loop
//     (R0 structure) restored under the cap with no spill.
//  LDS/block: 4*16*129*8 + sCS + sI4 = 75776 B; 2 blocks/CU = 148 KB <= 160.
__global__ __launch_bounds__(256,2) void rvq_main(
    const float* __restrict__ x, const float* __restrict__ cb,
    const float* __restrict__ sumsq, double* __restrict__ lossAcc,
    float* __restrict__ out)
{
  __shared__ double sR[4][16][129];  // fp64 residual master, padded stride
  __shared__ float sCS[4][16][34];   // per-wave packed top2 scores (stride 34)
  __shared__ int   sI4[4][16][4];    // per-row top-4 global code ids

  const int tid  = threadIdx.x;
  const int wv   = tid>>6;
  const int ln   = tid&63;
  const int col  = ln&15;
  const int quad = ln>>4;
  const int blk  = blockIdx.x;
  const int b    = blk>>6;
  const int t0   = ((blk&63)<<6) + (wv<<4);
  const int t    = t0 + col;

  // residual: fp64 master in LDS, fp32 shadow in regs.
  // A-frag distribution: row = col, dim = kc*32+quad*8+j
  float rs[4][8];
#pragma unroll
  for (int kc=0;kc<4;++kc)
#pragma unroll
    for (int j=0;j<8;++j){
      const int d = kc*32 + quad*8 + j;
      const double v = (double)x[((size_t)b*D_ + d)*T_ + t];
      sR[wv][col][d] = v;
      rs[kc][j] = (float)v;
    }

  half8 ah[4];
  auto makeAB = [&](){
#pragma unroll
    for (int kc=0;kc<4;++kc){
      half8 h;
#pragma unroll
      for (int j=0;j<8;++j) h[j] = (_Float16)rs[kc][j];
      ah[kc] = h;
    }
  };
  makeAB();

  double lossd = 0.0;

  // register pipeline buffers: B-fragments + cc for one group (32 codes)
  half8 bufA[8], bufB[8];
  float ccA[2],  ccB[2];

  auto loadGroup = [&](const _Float16* cbh, const float* ssq, int g, half8* Bv, float* cc){
#pragma unroll
    for (int kc=0;kc<4;++kc)
#pragma unroll
      for (int ct=0;ct<2;++ct){
        const int n = g*32 + ct*16 + col;
        Bv[kc*2+ct] = *(const half8*)(cbh + n*128 + kc*32 + quad*8);
      }
#pragma unroll
    for (int ct=0;ct<2;++ct)
      cc[ct] = ssq[(g*2+ct)*16 + col];
  };

  loadGroup(g_half, sumsq, 0, bufA, ccA);   // prologue: q=0, group 0

  for (int q=0;q<Q_;++q){
    const float*    cbq = cb     + (size_t)q*C_*D_;
    const _Float16* cbh = g_half + (size_t)q*C_*D_;
    const float*    ssq = sumsq  + q*C_;

    // packed top-2 per cell: score float with low 6 mantissa bits = cid (0..63)
    float p1[4], p2[4];
#pragma unroll
    for (int rg=0;rg<4;++rg){ p1[rg]=3.0e38f; p2[rg]=3.0e38f; }

#pragma unroll
    for (int g=0; g<32; ++g){
      half8* cur = (g&1) ? bufB : bufA;
      float* ccc = (g&1) ? ccB  : ccA;
      // prefetch next group (codebook loads independent of residual —
      // cross-q prefetch of (q+1, group 0) overlaps the q-tail)
      if (g < 31){
        loadGroup(cbh, ssq, g+1, (g&1)?bufA:bufB, (g&1)?ccA:ccB);
      } else if (q+1 < Q_){
        loadGroup(cbh + C_*D_, ssq + C_, 0, (g&1)?bufA:bufB, (g&1)?ccA:ccB);
      }

      float4_ acc[2];
#pragma unroll
      for (int ct=0;ct<2;++ct) acc[ct] = (float4_){0.f,0.f,0.f,0.f};
#pragma unroll
      for (int kc=0;kc<4;++kc)
#pragma unroll
        for (int ct=0;ct<2;++ct)
          acc[ct] = __builtin_amdgcn_mfma_f32_16x16x32_f16(ah[kc], cur[kc*2+ct], acc[ct], 0,0,0);

#pragma unroll
      for (int ct=0;ct<2;++ct){
        const int cid = g*2 + ct;                      // global code = cid*16+col
#pragma unroll
        for (int rg=0;rg<4;++rg){
          float sc = fmaf(-2.0f, acc[ct][rg], ccc[ct]);
          unsigned u = (__builtin_bit_cast(unsigned, sc) & ~63u) | (unsigned)cid;
          float sp = __builtin_bit_cast(float, u);
          if (sp < p1[rg]) { p2[rg]=p1[rg]; p1[rg]=sp; }
          else if (sp < p2[rg]) { p2[rg]=sp; }
        }
      }
    }

    // ---- publish per-lane packed top-2 (wave-private, lockstep) ----
#pragma unroll
    for (int rg=0;rg<4;++rg){
      const int row = quad*4 + rg;
      sCS[wv][row][col*2+0] = p1[rg];
      sCS[wv][row][col*2+1] = p2[rg];
    }

    // ---- lanes 0..15: scan own row's 32 packed entries -> top-4 ids ----
    if (ln < 16){
      const int row = ln;
      float b0=3.0e38f,b1=3.0e38f,b2=3.0e38f,b3=3.0e38f;
      int   e0=0,e1=0,e2=0,e3=0;
#pragma unroll
      for (int c2=0;c2<32;++c2){
        const float sc = sCS[wv][row][c2];
        const int   id = (((__builtin_bit_cast(unsigned, sc)) & 63u)<<4) + (c2>>1);
        const bool l0 = (sc<b0);
        const bool l1 = (sc<b1);
        const bool l2 = (sc<b2);
        const bool l3 = (sc<b3);
        if (l3){
          b3 = l2 ? b2 : sc;  e3 = l2 ? e2 : id;
          if (l2){
            b2 = l1 ? b1 : sc;  e2 = l1 ? e1 : id;
            if (l1){
              b1 = l0 ? b0 : sc;  e1 = l0 ? e0 : id;
              if (l0){ b0 = sc; e0 = id; }
            }
          }
        }
      }
      sI4[wv][row][0]=e0; sI4[wv][row][1]=e1; sI4[wv][row][2]=e2; sI4[wv][row][3]=e3;
    }

    // ---- fp64 exact rescore of top-4 (rmast read once, shared by 4 cands) ---
    {
      const int jj0 = sI4[wv][col][0];
      const int jj1 = sI4[wv][col][1];
      const int jj2 = sI4[wv][col][2];
      const int jj3 = sI4[wv][col][3];
      double sd0=0.0, sd1=0.0, sd2=0.0, sd3=0.0;
#pragma unroll
      for (int kc=0;kc<4;++kc){
        float fv0[8], fv1[8], fv2[8], fv3[8];
        {
          const float* p0 = cbq + ((size_t)jj0<<7) + (quad<<3) + kc*32;
          const float* p1p = cbq + ((size_t)jj1<<7) + (quad<<3) + kc*32;
          const float* p2p = cbq + ((size_t)jj2<<7) + (quad<<3) + kc*32;
          const float* p3p = cbq + ((size_t)jj3<<7) + (quad<<3) + kc*32;
          float4_ a0 = *(const float4_*)(p0),  a1 = *(const float4_*)(p0+4);
          float4_ b0v= *(const float4_*)(p1p), b1v= *(const float4_*)(p1p+4);
          float4_ c0 = *(const float4_*)(p2p), c1 = *(const float4_*)(p2p+4);
          float4_ d0 = *(const float4_*)(p3p), d1 = *(const float4_*)(p3p+4);
          fv0[0]=a0.x;fv0[1]=a0.y;fv0[2]=a0.z;fv0[3]=a0.w;fv0[4]=a1.x;fv0[5]=a1.y;fv0[6]=a1.z;fv0[7]=a1.w;
          fv1[0]=b0v.x;fv1[1]=b0v.y;fv1[2]=b0v.z;fv1[3]=b0v.w;fv1[4]=b1v.x;fv1[5]=b1v.y;fv1[6]=b1v.z;fv1[7]=b1v.w;
          fv2[0]=c0.x;fv2[1]=c0.y;fv2[2]=c0.z;fv2[3]=c0.w;fv2[4]=c1.x;fv2[5]=c1.y;fv2[6]=c1.z;fv2[7]=c1.w;
          fv3[0]=d0.x;fv3[1]=d0.y;fv3[2]=d0.z;fv3[3]=d0.w;fv3[4]=d1.x;fv3[5]=d1.y;fv3[6]=d1.z;fv3[7]=d1.w;
        }
#pragma unroll
        for (int j=0;j<8;++j){
          const double r2 = 2.0 * sR[wv][col][kc*32 + quad*8 + j];
          double cd;
          cd = (double)fv0[j]; sd0 += cd*(cd - r2);
          cd = (double)fv1[j]; sd1 += cd*(cd - r2);
          cd = (double)fv2[j]; sd2 += cd*(cd - r2);
          cd = (double)fv3[j]; sd3 += cd*(cd - r2);
        }
      }
      sd0 += __shfl_xor(sd0,16); sd0 += __shfl_xor(sd0,32);
      sd1 += __shfl_xor(sd1,16); sd1 += __shfl_xor(sd1,32);
      sd2 += __shfl_xor(sd2,16); sd2 += __shfl_xor(sd2,32);
      sd3 += __shfl_xor(sd3,16); sd3 += __shfl_xor(sd3,32);

      double bestS = sd0; int bestJ = jj0;
      if ((sd1 < bestS) || (sd1 == bestS && jj1 < bestJ)){ bestS = sd1; bestJ = jj1; }
      if ((sd2 < bestS) || (sd2 == bestS && jj2 < bestJ)){ bestS = sd2; bestJ = jj2; }
      if ((sd3 < bestS) || (sd3 == bestS && jj3 < bestJ)){ bestS = sd3; bestJ = jj3; }

      // ---- winner update: fp64 master in LDS, fp32 shadow refresh ----------
      const float* pw = cbq + ((size_t)bestJ<<7) + (quad<<3);
#pragma unroll
      for (int kc=0;kc<4;++kc){
        float4_ w0 = *(const float4_*)(pw + kc*32);
        float4_ w1 = *(const float4_*)(pw + kc*32 + 4);
        float fw[8] = {w0.x,w0.y,w0.z,w0.w,w1.x,w1.y,w1.z,w1.w};
#pragma unroll
        for (int j=0;j<8;++j){
          const int d = kc*32 + quad*8 + j;
          const double rn = sR[wv][col][d] - (double)fw[j];
          sR[wv][col][d] = rn;
          rs[kc][j] = (float)rn;
          lossd += rn*rn;
        }
      }
    }
    makeAB();
  }

  // ---- epilogue: quantized = x - r_final ----
#pragma unroll
  for (int kc=0;kc<4;++kc)
#pragma unroll
    for (int j=0;j<8;++j){
      const int d = kc*32 + quad*8 + j;
      const size_t o = ((size_t)b*D_ + d)*T_ + t;
      out[o] = (float)((double)x[o] - sR[wv][col][d]);
    }
#pragma unroll
  for (int mk=1; mk<64; mk<<=1) lossd += __shfl_xor(lossd, mk);
  if (ln==0) atomicAdd(lossAcc, lossd);
}

__global__ void rvq_fin(const double* __restrict__ lossAcc, float* __restrict__ out){
  out[(size_t)B_*D_*T_] = (float)(*lossAcc * (1.0/((double)B_*(double)D_*(double)T_)));
}

extern "C" void kernel_launch(void* const* d_in, const int* in_sizes, int n_in,
                              void* d_out, int out_size, void* d_ws, size_t ws_size,
                              hipStream_t stream) {
  const float* x  = (const float*)d_in[0];   // [B, D, T] fp32
  const float* cb = (const float*)d_in[1];   // [Q, C, D] fp32
  float* out      = (float*)d_out;           // [B*D*T] quantized + [1] loss
  double* lossAcc = (double*)d_ws;
  float*  sumsq   = (float*)((char*)d_ws + 256);   // Q*C floats

  hipMemsetAsync(d_ws, 0, 256, stream);
  rvq_prep<<<Q_*C_/128, 256, 0, stream>>>(cb, sumsq);
  rvq_h   <<<(Q_*C_*D_)/(256*8), 256, 0, stream>>>(cb);
  rvq_main<<<(B_*T_)/64, 256, 0, stream>>>(x, cb, sumsq, lossAcc, out);
  rvq_fin <<<1, 1, 0, stream>>>(lossAcc, out);
}